// Round 1
// 268.430 us; speedup vs baseline: 1.0834x; 1.0834x over previous
//
#include <hip/hip_runtime.h>
#include <hip/hip_bf16.h>

// ---- problem constants ----
#define L_IN   220500
#define PADK   1024
#define LP     222548            // L_IN + 2048 (reflect-padded length)
#define LPP    222560            // LP rounded up to 16B-aligned rows
#define BATCH  32
#define HOPSZ  512
#define T_FR   431               // frames per batch
#define F_BINS 1025
#define M_TOT  (BATCH * T_FR)    // 13792 frames
#define N_GEMM 2048              // interleaved rows n' = 2k + c for k = 0..1023
#define K_TOT  2048
#define NT_K   32                // K tiles of 64

typedef short short8 __attribute__((ext_vector_type(8)));
typedef float floatx4 __attribute__((ext_vector_type(4)));

__device__ __forceinline__ void glds16(const void* g, void* l) {
    __builtin_amdgcn_global_load_lds(
        (const __attribute__((address_space(1))) void*)g,
        (__attribute__((address_space(3))) void*)l, 16, 0, 0);
}

__device__ __forceinline__ short f2bf(float f) {
    __hip_bfloat16 h = __float2bfloat16(f);
    return *reinterpret_cast<short*>(&h);
}

// ---- pass 1a: reflect-pad + f32->bf16, 8 elems/thread ----
__global__ void k_prep_x(const float* __restrict__ x, __hip_bfloat16* __restrict__ xp) {
    int c = blockIdx.x * 256 + threadIdx.x;
    int b = blockIdx.y;
    int i0 = c * 8;
    if (i0 >= LP) return;
    const float* xb = x + (size_t)b * L_IN;
    __hip_bfloat16* xpb = xp + (size_t)b * LPP;
    if (i0 >= PADK && i0 + 8 <= PADK + L_IN) {
        const float4* s4 = (const float4*)(xb + (i0 - PADK));
        float4 a = s4[0], d = s4[1];
        short8 o;
        o[0]=f2bf(a.x); o[1]=f2bf(a.y); o[2]=f2bf(a.z); o[3]=f2bf(a.w);
        o[4]=f2bf(d.x); o[5]=f2bf(d.y); o[6]=f2bf(d.z); o[7]=f2bf(d.w);
        *(short8*)((short*)xpb + i0) = o;
    } else {
        for (int u = 0; u < 8; ++u) {
            int i = i0 + u;
            if (i >= LP) break;
            int j = i - PADK;
            if (j < 0) j = -j;
            if (j >= L_IN) j = 2 * L_IN - 2 - j;
            xpb[i] = __float2bfloat16(xb[j]);
        }
    }
}

// ---- pass 1b: interleave wcos/wsin -> bf16 [2048][2048], row n' = 2k + c ----
__global__ void k_prep_w(const float* __restrict__ wcos, const float* __restrict__ wsin,
                         __hip_bfloat16* __restrict__ wb) {
    int c = blockIdx.x * 256 + threadIdx.x;   // 8-elem chunk; one row per block
    int i0 = c * 8;
    if (i0 >= N_GEMM * K_TOT) return;
    int np = i0 >> 11;
    int k  = i0 & (K_TOT - 1);
    int kf = np >> 1;
    const float* src = ((np & 1) ? wsin : wcos) + (size_t)kf * K_TOT + k;
    float4 a = ((const float4*)src)[0], d = ((const float4*)src)[1];
    short8 o;
    o[0]=f2bf(a.x); o[1]=f2bf(a.y); o[2]=f2bf(a.z); o[3]=f2bf(a.w);
    o[4]=f2bf(d.x); o[5]=f2bf(d.y); o[6]=f2bf(d.z); o[7]=f2bf(d.w);
    *(short8*)((short*)wb + i0) = o;
}

// ---- Nyquist bin k=1024: wsin row is sin(pi*s) == 0, so imag == 0 and
// real = sum_s x[s+t*512] * wcos1024[s]. One wave per frame. ----
__global__ void k_nyq(const __hip_bfloat16* __restrict__ xp, const float* __restrict__ wcos,
                      float* __restrict__ out) {
    int f = blockIdx.x * 4 + (threadIdx.x >> 6);
    if (f >= M_TOT) return;
    int lane = threadIdx.x & 63;
    int b = f / T_FR, t = f - b * T_FR;
    const __hip_bfloat16* xr = xp + (size_t)b * LPP + t * HOPSZ;
    const float* wr = wcos + (size_t)1024 * K_TOT;
    float sum = 0.f;
    #pragma unroll
    for (int i = 0; i < 4; ++i) {
        int s = i * 512 + lane * 8;
        short8 xv = *(const short8*)((const short*)xr + s);
        const float4* wv = (const float4*)(wr + s);
        float4 w0 = wv[0], w1 = wv[1];
        float xs[8];
        #pragma unroll
        for (int u = 0; u < 8; ++u)
            xs[u] = __uint_as_float(((unsigned)(unsigned short)xv[u]) << 16);
        sum += xs[0]*w0.x + xs[1]*w0.y + xs[2]*w0.z + xs[3]*w0.w
             + xs[4]*w1.x + xs[5]*w1.y + xs[6]*w1.z + xs[7]*w1.w;
    }
    #pragma unroll
    for (int off = 32; off > 0; off >>= 1) sum += __shfl_xor(sum, off);
    if (lane == 0) {
        float2 v; v.x = sum; v.y = 0.f;
        ((float2*)out)[((size_t)b * F_BINS + 1024) * T_FR + t] = v;
    }
}

// ---- pass 2: 256x256 8-phase deep-pipelined bf16 MFMA GEMM (C^T), counted vmcnt ----
// LDS 128 KiB: A[buf][half][128][64] at 0, B[buf][half][128][64] at 32768 shorts.
// Chunk swizzle (conflict-free, same as verified predecessor):
//   LDS[row][c] = global[row][c ^ (row&7)] over 16B chunks (8 per 64-elem row).
// Phases per K-tile (BK=64): (qm,qn) C-quadrant; xf persists across qn, wf0/wf1
// persist across qm -> minimal 24 ds_read_b128 per tile per wave.
// Staging: 1 half-tile (2 glds/wave) per phase, targeting regions whose last LDS
// read completed >=1 barrier ago:
//   s0: A[buf^1][1] for tile T+1   s1: A[buf][0] for T+2
//   s2: B[buf][0]  for T+2         s3: B[buf][1] for T+2
// Boundary wait: vmcnt(6) (= 3 newest half-tiles in flight) before the s3 trailing
// barrier guarantees tile T+1 fully landed; T==30 boundary drains with vmcnt(0).
#define BARRIER { asm volatile("" ::: "memory"); __builtin_amdgcn_s_barrier(); asm volatile("" ::: "memory"); }
#define LGKM0   asm volatile("s_waitcnt lgkmcnt(0)" ::: "memory")
#define SP1     __builtin_amdgcn_s_setprio(1)
#define SP0     __builtin_amdgcn_s_setprio(0)

__global__ __launch_bounds__(512, 2) void k_gemm(
    const __hip_bfloat16* __restrict__ xp,
    const __hip_bfloat16* __restrict__ wb,
    float* __restrict__ out) {

    __shared__ short lds[65536];   // 128 KiB

    const int tid   = threadIdx.x;
    const int wave  = tid >> 6;
    const int lane  = tid & 63;
    const int quad  = lane >> 4;
    const int l15   = lane & 15;
    const int waveM = wave >> 2;   // 2(M) x 4(N) wave grid, each wave: (2x64)m x (2x32)n'
    const int waveN = wave & 3;

    // XCD swizzle: grid 432 = 8 XCDs x 54; one bn column per XCD (B-panel L2-resident)
    const int bn = blockIdx.x & 7;
    const int bm = blockIdx.x >> 3;

    // staging source offsets (elements), per (half, issue)
    int arow[2][2], brow[2][2];
    #pragma unroll
    for (int h = 0; h < 2; ++h)
        #pragma unroll
        for (int q = 0; q < 2; ++q) {
            int m = bm * 256 + h * 128 + wave * 16 + q * 8 + (lane >> 3);
            if (m > M_TOT - 1) m = M_TOT - 1;          // clamp; masked at store
            int b = m / T_FR, t = m - b * T_FR;
            arow[h][q] = b * LPP + t * HOPSZ;
            int n = bn * 256 + h * 128 + wave * 16 + q * 8 + (lane >> 3);   // <= 2047
            brow[h][q] = n * K_TOT;
        }
    const int colo = (((lane & 7) ^ (lane >> 3)) << 3);   // pre-swizzled global chunk

#define STA(BUF,H,K0) { _Pragma("unroll") for (int q = 0; q < 2; ++q) \
        glds16(xp + arow[H][q] + (K0) + colo, &lds[((BUF)<<14) + ((H)<<13) + (wave*16 + q*8)*64]); }
#define STB(BUF,H,K0) { _Pragma("unroll") for (int q = 0; q < 2; ++q) \
        glds16(wb + brow[H][q] + (K0) + colo, &lds[32768 + ((BUF)<<14) + ((H)<<13) + (wave*16 + q*8)*64]); }
#define RDA(BUF,H) { _Pragma("unroll") for (int jm = 0; jm < 4; ++jm) { \
        int R = waveM*64 + jm*16 + l15; \
        _Pragma("unroll") for (int ks = 0; ks < 2; ++ks) \
            xf[jm][ks] = *(const short8*)&lds[((BUF)<<14) + ((H)<<13) + R*64 + (((ks*4+quad) ^ (R & 7)) << 3)]; } }
#define RDB(BUF,H,WF) { _Pragma("unroll") for (int jn = 0; jn < 2; ++jn) { \
        int R = waveN*32 + jn*16 + l15; \
        _Pragma("unroll") for (int ks = 0; ks < 2; ++ks) \
            WF[jn][ks] = *(const short8*)&lds[32768 + ((BUF)<<14) + ((H)<<13) + R*64 + (((ks*4+quad) ^ (R & 7)) << 3)]; } }
#define MFMA16(ACC, WF) { _Pragma("unroll") for (int jm = 0; jm < 4; ++jm) \
        _Pragma("unroll") for (int jn = 0; jn < 2; ++jn) \
        _Pragma("unroll") for (int ks = 0; ks < 2; ++ks) \
            ACC[jm][jn] = __builtin_amdgcn_mfma_f32_16x16x32_bf16(WF[jn][ks], xf[jm][ks], ACC[jm][jn], 0, 0, 0); }

    short8 xf[4][2], wf0[2][2], wf1[2][2];
    floatx4 a00[4][2] = {}, a01[4][2] = {}, a10[4][2] = {}, a11[4][2] = {};

    // prologue: tile0 fully + tile1's first 3 half-tiles, in steady-state stream order
    STA(0,0,0); STB(0,0,0); STB(0,1,0); STA(0,1,0);
    STA(1,0,64); STB(1,0,64); STB(1,1,64);
    asm volatile("s_waitcnt vmcnt(6)" ::: "memory");   // tile 0 landed
    BARRIER;

#define TILE(T, BUF) { \
    /* s0: quadrant (qm=0,qn=0) */ \
    RDA(BUF, 0); RDB(BUF, 0, wf0); \
    if ((T) + 1 < NT_K) STA(BUF^1, 1, ((T)+1)*64); \
    BARRIER; LGKM0; SP1; MFMA16(a00, wf0); SP0; BARRIER; \
    /* s1: (0,1) */ \
    RDB(BUF, 1, wf1); \
    if ((T) + 2 < NT_K) STA(BUF, 0, ((T)+2)*64); \
    BARRIER; LGKM0; SP1; MFMA16(a01, wf1); SP0; BARRIER; \
    /* s2: (1,0) */ \
    RDA(BUF, 1); \
    if ((T) + 2 < NT_K) STB(BUF, 0, ((T)+2)*64); \
    BARRIER; LGKM0; SP1; MFMA16(a10, wf0); SP0; BARRIER; \
    /* s3: (1,1) + tile boundary */ \
    if ((T) + 2 < NT_K) STB(BUF, 1, ((T)+2)*64); \
    BARRIER; LGKM0; SP1; MFMA16(a11, wf1); SP0; \
    if ((T) == NT_K - 2) { asm volatile("s_waitcnt vmcnt(0)" ::: "memory"); } \
    else                 { asm volatile("s_waitcnt vmcnt(6)" ::: "memory"); } \
    BARRIER; \
}

    #pragma unroll 1
    for (int T = 0; T < NT_K; T += 2) {
        TILE(T, 0);
        TILE(T + 1, 1);
    }

    // epilogue: C^T; lane&15 = m (consecutive t), regs = consecutive n' = (k, re/im)
    float2* __restrict__ out2 = (float2*)out;
#define EPI(ACC, QM, QN) { _Pragma("unroll") for (int jm = 0; jm < 4; ++jm) { \
        int m = bm*256 + QM*128 + waveM*64 + jm*16 + l15; \
        if (m < M_TOT) { \
            int b = m / T_FR, t = m - b * T_FR; \
            long tbase = (long)b * (F_BINS * T_FR) + t; \
            _Pragma("unroll") for (int jn = 0; jn < 2; ++jn) { \
                int nb = bn*256 + QN*128 + waveN*32 + jn*16 + quad*4; \
                _Pragma("unroll") for (int p = 0; p < 2; ++p) { \
                    int k = (nb + 2*p) >> 1; \
                    float2 v; v.x = ACC[jm][jn][2*p]; v.y = -ACC[jm][jn][2*p+1]; \
                    out2[tbase + (long)k * T_FR] = v; \
                } } } } }
    EPI(a00, 0, 0); EPI(a01, 0, 1); EPI(a10, 1, 0); EPI(a11, 1, 1);
}

extern "C" void kernel_launch(void* const* d_in, const int* in_sizes, int n_in,
                              void* d_out, int out_size, void* d_ws, size_t ws_size,
                              hipStream_t stream) {
    const float* x    = (const float*)d_in[0];
    const float* wcos = (const float*)d_in[1];
    const float* wsin = (const float*)d_in[2];
    float* out = (float*)d_out;

    // ws: xp bf16 [32][LPP] then wb bf16 [2048][2048]  (~22.6 MB)
    __hip_bfloat16* xp = (__hip_bfloat16*)d_ws;
    __hip_bfloat16* wb = (__hip_bfloat16*)((char*)d_ws + (size_t)BATCH * LPP * sizeof(__hip_bfloat16));

    const int xchunks = (LP + 7) / 8;                       // 27819
    k_prep_x<<<dim3((xchunks + 255) / 256, BATCH), 256, 0, stream>>>(x, xp);
    k_prep_w<<<(N_GEMM * K_TOT / 8) / 256, 256, 0, stream>>>(wcos, wsin, wb);
    k_gemm<<<432, 512, 0, stream>>>(xp, wb, out);           // 54 m-tiles x 8 n-tiles
    k_nyq<<<(M_TOT + 3) / 4, 256, 0, stream>>>(xp, wcos, out);
}

// Round 2
// 259.616 us; speedup vs baseline: 1.1202x; 1.0339x over previous
//
#include <hip/hip_runtime.h>
#include <hip/hip_bf16.h>

// ---- problem constants ----
#define L_IN   220500
#define PADK   1024
#define LP     222548            // L_IN + 2048 (reflect-padded length)
#define LPP    222560            // LP rounded up to 16B-aligned rows
#define BATCH  32
#define HOPSZ  512
#define T_FR   431               // frames per batch
#define F_BINS 1025
#define M_TOT  (BATCH * T_FR)    // 13792 frames
#define N_GEMM 2048              // interleaved rows n' = 2k + c for k = 0..1023
#define K_TOT  2048
#define NT_K   32                // K tiles of 64
#define GEMM_BLOCKS 432          // 54 m-tiles x 8 n-tiles
#define NYQ_BLOCKS  48
#define XBLOCKS 3488             // 109 per batch x 32
#define WBLOCKS 2048

typedef short short8 __attribute__((ext_vector_type(8)));
typedef float floatx4 __attribute__((ext_vector_type(4)));

__device__ __forceinline__ void glds16(const void* g, void* l) {
    __builtin_amdgcn_global_load_lds(
        (const __attribute__((address_space(1))) void*)g,
        (__attribute__((address_space(3))) void*)l, 16, 0, 0);
}

__device__ __forceinline__ short f2bf(float f) {
    __hip_bfloat16 h = __float2bfloat16(f);
    return *reinterpret_cast<short*>(&h);
}

// ---- pass 1: fused reflect-pad x->bf16 (blocks 0..3487) + weight interleave (3488..5535)
__global__ void k_prep(const float* __restrict__ x,
                       const float* __restrict__ wcos, const float* __restrict__ wsin,
                       __hip_bfloat16* __restrict__ xp, __hip_bfloat16* __restrict__ wb) {
    int blk = blockIdx.x;
    if (blk < XBLOCKS) {
        int b = blk / 109, ix = blk - b * 109;
        int i0 = (ix * 256 + threadIdx.x) * 8;
        if (i0 >= LP) return;
        const float* xb = x + (size_t)b * L_IN;
        __hip_bfloat16* xpb = xp + (size_t)b * LPP;
        if (i0 >= PADK && i0 + 8 <= PADK + L_IN) {
            const float4* s4 = (const float4*)(xb + (i0 - PADK));
            float4 a = s4[0], d = s4[1];
            short8 o;
            o[0]=f2bf(a.x); o[1]=f2bf(a.y); o[2]=f2bf(a.z); o[3]=f2bf(a.w);
            o[4]=f2bf(d.x); o[5]=f2bf(d.y); o[6]=f2bf(d.z); o[7]=f2bf(d.w);
            *(short8*)((short*)xpb + i0) = o;
        } else {
            for (int u = 0; u < 8; ++u) {
                int i = i0 + u;
                if (i >= LP) break;
                int j = i - PADK;
                if (j < 0) j = -j;
                if (j >= L_IN) j = 2 * L_IN - 2 - j;
                xpb[i] = __float2bfloat16(xb[j]);
            }
        }
    } else {
        int i0 = ((blk - XBLOCKS) * 256 + threadIdx.x) * 8;   // < 2048*2048 exactly
        int np = i0 >> 11;
        int k  = i0 & (K_TOT - 1);
        int kf = np >> 1;
        const float* src = ((np & 1) ? wsin : wcos) + (size_t)kf * K_TOT + k;
        float4 a = ((const float4*)src)[0], d = ((const float4*)src)[1];
        short8 o;
        o[0]=f2bf(a.x); o[1]=f2bf(a.y); o[2]=f2bf(a.z); o[3]=f2bf(a.w);
        o[4]=f2bf(d.x); o[5]=f2bf(d.y); o[6]=f2bf(d.z); o[7]=f2bf(d.w);
        *(short8*)((short*)wb + i0) = o;
    }
}

// ---- pass 2: 256x256 bf16 MFMA GEMM (C^T), read-after-consume fragment pipeline,
// trailing-only barriers, counted vmcnt. Nyquist bin k=1024 handled by 48 tail
// blocks (blockIdx >= 432) that fill the 432-on-256-CU second-round bubble.
//
// LDS 128 KiB: A[buf][half][128][64] at 0, B[buf][half][128][64] at 32768 shorts.
// Chunk swizzle: LDS[row][c16] = global[row][c16 ^ (row&7)]  (conflict-free, verified).
//
// Phase schedule per K-tile T (buf B = T&1), ONE barrier per phase:
//  s0: [pre-read wf1<-Bw[B][1]; stage A[B^1][1] (T+1)]  MFMA a00(wf0,xf_h0)           BAR
//  s1: [stage A[B][0] (T+2)]  MFMA a01(wf1,xf_h0)  post-read xf<-A[B][1] (WAR-safe)   BAR
//  s2: [stage Bw[B][0] (T+2)] MFMA a10(wf0,xf_h1)  vmcnt(8|4)                          BAR
//  s3: [pre-read wf0'<-Bw[B'][0]; stage Bw[B][1] (T+2)] MFMA a11(wf1,xf_h1)
//      post-read xf<-A[B'][0]  vmcnt(6|0)                                              BAR
// Visibility proofs: each read's staged source is covered by the most recent
// all-wave {vmcnt + barrier}: s0.pre/s1.post by the tile boundary vmcnt(6) (retires
// through T-1.s1 >= staged T-2.s3 / T-1.s0); s3.pre/s3.post by s2's vmcnt(8)
// (retires through T-1.s2 >= staged T-1.s1/s2). Edge tiles: T=30 uses vmcnt(4)/(0).
// Clobber proofs: every staging glds targets a region whose last ds_read retired
// before a barrier that precedes the glds issue (>=1 trailing barrier in between).
#define BARRIER { asm volatile("" ::: "memory"); __builtin_amdgcn_s_barrier(); asm volatile("" ::: "memory"); }
#define VMW(N)  asm volatile("s_waitcnt vmcnt(" #N ")" ::: "memory")
#define SCHED0  __builtin_amdgcn_sched_barrier(0)
#define SP1     __builtin_amdgcn_s_setprio(1)
#define SP0     __builtin_amdgcn_s_setprio(0)

__global__ __launch_bounds__(512, 2) void k_gemm(
    const __hip_bfloat16* __restrict__ xp,
    const __hip_bfloat16* __restrict__ wb,
    const float* __restrict__ wcos,
    float* __restrict__ out) {

    __shared__ short lds[65536];   // 128 KiB

    const int tid   = threadIdx.x;
    const int wave  = tid >> 6;
    const int lane  = tid & 63;

    // ---- Nyquist tail blocks: k=1024 row (wsin==0 -> imag==0) ----
    if (blockIdx.x >= GEMM_BLOCKS) {
        const int gw = (blockIdx.x - GEMM_BLOCKS) * 8 + wave;   // 0..383
        const float* wr = wcos + (size_t)1024 * K_TOT;
        for (int f = gw; f < M_TOT; f += NYQ_BLOCKS * 8) {
            int b = f / T_FR, t = f - b * T_FR;
            const __hip_bfloat16* xr = xp + (size_t)b * LPP + t * HOPSZ;
            float sum = 0.f;
            #pragma unroll
            for (int i = 0; i < 4; ++i) {
                int s = i * 512 + lane * 8;
                short8 xv = *(const short8*)((const short*)xr + s);
                const float4* wv = (const float4*)(wr + s);
                float4 w0 = wv[0], w1 = wv[1];
                float xs[8];
                #pragma unroll
                for (int u = 0; u < 8; ++u)
                    xs[u] = __uint_as_float(((unsigned)(unsigned short)xv[u]) << 16);
                sum += xs[0]*w0.x + xs[1]*w0.y + xs[2]*w0.z + xs[3]*w0.w
                     + xs[4]*w1.x + xs[5]*w1.y + xs[6]*w1.z + xs[7]*w1.w;
            }
            #pragma unroll
            for (int off = 32; off > 0; off >>= 1) sum += __shfl_xor(sum, off);
            if (lane == 0) {
                float2 v; v.x = sum; v.y = 0.f;
                ((float2*)out)[((size_t)b * F_BINS + 1024) * T_FR + t] = v;
            }
        }
        return;
    }

    const int quad  = lane >> 4;
    const int l15   = lane & 15;
    const int waveM = wave >> 2;   // 2(M) x 4(N) wave grid
    const int waveN = wave & 3;

    // XCD swizzle: 432 gemm blocks; bn = blockIdx&7 == XCD id -> B-panel L2-resident
    const int bn = blockIdx.x & 7;
    const int bm = blockIdx.x >> 3;

    int arow[2][2], brow[2][2];
    #pragma unroll
    for (int h = 0; h < 2; ++h)
        #pragma unroll
        for (int q = 0; q < 2; ++q) {
            int m = bm * 256 + h * 128 + wave * 16 + q * 8 + (lane >> 3);
            if (m > M_TOT - 1) m = M_TOT - 1;          // clamp; masked at store
            int b = m / T_FR, t = m - b * T_FR;
            arow[h][q] = b * LPP + t * HOPSZ;
            int n = bn * 256 + h * 128 + wave * 16 + q * 8 + (lane >> 3);   // <= 2047
            brow[h][q] = n * K_TOT;
        }
    const int colo = (((lane & 7) ^ (lane >> 3)) << 3);   // pre-swizzled global chunk

#define STA(BUF,H,K0) { _Pragma("unroll") for (int q = 0; q < 2; ++q) \
        glds16(xp + arow[H][q] + (K0) + colo, &lds[((BUF)<<14) + ((H)<<13) + (wave*16 + q*8)*64]); }
#define STB(BUF,H,K0) { _Pragma("unroll") for (int q = 0; q < 2; ++q) \
        glds16(wb + brow[H][q] + (K0) + colo, &lds[32768 + ((BUF)<<14) + ((H)<<13) + (wave*16 + q*8)*64]); }
#define RDA(BUF,H) { _Pragma("unroll") for (int jm = 0; jm < 4; ++jm) { \
        int R = waveM*64 + jm*16 + l15; \
        _Pragma("unroll") for (int ks = 0; ks < 2; ++ks) \
            xf[jm][ks] = *(const short8*)&lds[((BUF)<<14) + ((H)<<13) + R*64 + (((ks*4+quad) ^ (R & 7)) << 3)]; } }
#define RDB(BUF,H,WF) { _Pragma("unroll") for (int jn = 0; jn < 2; ++jn) { \
        int R = waveN*32 + jn*16 + l15; \
        _Pragma("unroll") for (int ks = 0; ks < 2; ++ks) \
            WF[jn][ks] = *(const short8*)&lds[32768 + ((BUF)<<14) + ((H)<<13) + R*64 + (((ks*4+quad) ^ (R & 7)) << 3)]; } }
#define MFMA16(ACC, WF) { _Pragma("unroll") for (int jm = 0; jm < 4; ++jm) \
        _Pragma("unroll") for (int jn = 0; jn < 2; ++jn) \
        _Pragma("unroll") for (int ks = 0; ks < 2; ++ks) \
            ACC[jm][jn] = __builtin_amdgcn_mfma_f32_16x16x32_bf16(WF[jn][ks], xf[jm][ks], ACC[jm][jn], 0, 0, 0); }

    short8 xf[4][2], wf0[2][2], wf1[2][2];
    floatx4 a00[4][2] = {}, a01[4][2] = {}, a10[4][2] = {}, a11[4][2] = {};

    // prologue: tile0 fully + tile1's first 3 half-tiles (steady-state stream order)
    STA(0,0,0); STB(0,0,0); STB(0,1,0); STA(0,1,0);
    STA(1,0,64); STB(1,0,64); STB(1,1,64);
    VMW(6);              // 14 in flight -> oldest 8 (all of tile 0) landed
    BARRIER;
    RDA(0,0); RDB(0,0,wf0);   // tile0 s0 operands

#define TILE(T, BUF) { \
    /* s0 */ \
    RDB(BUF, 1, wf1); \
    if ((T) + 1 < NT_K) STA(BUF^1, 1, ((T)+1)*64); \
    SCHED0; \
    SP1; MFMA16(a00, wf0); SP0; \
    BARRIER; \
    /* s1 */ \
    if ((T) + 2 < NT_K) STA(BUF, 0, ((T)+2)*64); \
    SCHED0; \
    SP1; MFMA16(a01, wf1); SP0; \
    RDA(BUF, 1); \
    BARRIER; \
    /* s2 */ \
    if ((T) + 2 < NT_K) STB(BUF, 0, ((T)+2)*64); \
    SCHED0; \
    SP1; MFMA16(a10, wf0); SP0; \
    if ((T) + 1 < NT_K) { if ((T) < NT_K - 2) { VMW(8); } else { VMW(4); } } \
    BARRIER; \
    /* s3 */ \
    if ((T) + 1 < NT_K) RDB(BUF^1, 0, wf0); \
    if ((T) + 2 < NT_K) STB(BUF, 1, ((T)+2)*64); \
    SCHED0; \
    SP1; MFMA16(a11, wf1); SP0; \
    if ((T) + 1 < NT_K) RDA(BUF^1, 0); \
    if ((T) == NT_K - 2) { VMW(0); } else if ((T) < NT_K - 2) { VMW(6); } \
    if ((T) + 1 < NT_K) BARRIER; \
}

    #pragma unroll 1
    for (int T = 0; T < NT_K; T += 2) {
        TILE(T, 0);
        TILE(T + 1, 1);
    }

    // epilogue: C^T; lane&15 = m (consecutive t), regs = consecutive n' = (k, re/im)
    float2* __restrict__ out2 = (float2*)out;
#define EPI(ACC, QM, QN) { _Pragma("unroll") for (int jm = 0; jm < 4; ++jm) { \
        int m = bm*256 + QM*128 + waveM*64 + jm*16 + l15; \
        if (m < M_TOT) { \
            int b = m / T_FR, t = m - b * T_FR; \
            long tbase = (long)b * (F_BINS * T_FR) + t; \
            _Pragma("unroll") for (int jn = 0; jn < 2; ++jn) { \
                int nb = bn*256 + QN*128 + waveN*32 + jn*16 + quad*4; \
                _Pragma("unroll") for (int p = 0; p < 2; ++p) { \
                    int k = (nb + 2*p) >> 1; \
                    float2 v; v.x = ACC[jm][jn][2*p]; v.y = -ACC[jm][jn][2*p+1]; \
                    out2[tbase + (long)k * T_FR] = v; \
                } } } } }
    EPI(a00, 0, 0); EPI(a01, 0, 1); EPI(a10, 1, 0); EPI(a11, 1, 1);
}

extern "C" void kernel_launch(void* const* d_in, const int* in_sizes, int n_in,
                              void* d_out, int out_size, void* d_ws, size_t ws_size,
                              hipStream_t stream) {
    const float* x    = (const float*)d_in[0];
    const float* wcos = (const float*)d_in[1];
    const float* wsin = (const float*)d_in[2];
    float* out = (float*)d_out;

    // ws: xp bf16 [32][LPP] then wb bf16 [2048][2048]  (~22.6 MB)
    __hip_bfloat16* xp = (__hip_bfloat16*)d_ws;
    __hip_bfloat16* wb = (__hip_bfloat16*)((char*)d_ws + (size_t)BATCH * LPP * sizeof(__hip_bfloat16));

    k_prep<<<XBLOCKS + WBLOCKS, 256, 0, stream>>>(x, wcos, wsin, xp, wb);
    k_gemm<<<GEMM_BLOCKS + NYQ_BLOCKS, 512, 0, stream>>>(xp, wb, wcos, out);
}